// Round 1
// baseline (60706.732 us; speedup 1.0000x reference)
//
#include <hip/hip_runtime.h>

// Problem constants
#define BATCH 32
#define TFULL 1024
#define HDIM  256
#define G4    1024   // 4*HDIM
#define TC    128    // timestep chunk
#define NWG   128    // scan workgroups (<=256 CUs -> co-resident)

// =====================================================================
// GEMM: xg[tl][n][b] = sum_k X[b, t0+tl, k] * W[n, k] + bia[n] + bib[n]
// Logical row m = tl*32 + b, m in [0, 4096). Tile 128x128, 512 threads,
// per-thread 4x8. K in {512, 256}, multiples of 16.
// =====================================================================
__global__ __launch_bounds__(512) void gemm_xg(
    const float* __restrict__ X, const float* __restrict__ W,
    const float* __restrict__ bia, const float* __restrict__ bib,
    float* __restrict__ xg, int K, int trows, int t0)
{
  __shared__ float Xs[16][128];
  __shared__ float Ws[16][128];
  const int tid = threadIdx.x;
  const int m0 = blockIdx.x * 128;
  const int n0 = blockIdx.y * 128;
  const int tx = tid & 15;      // n-dim: 8 cols each
  const int ty = tid >> 4;      // m-dim: 4 rows each (0..31)

  float acc[4][8];
#pragma unroll
  for (int i = 0; i < 4; ++i)
#pragma unroll
    for (int j = 0; j < 8; ++j) acc[i][j] = 0.f;

  // staging role: one float4 of X-tile and one of W-tile per thread
  const int r  = tid >> 2;      // 0..127 tile row
  const int kq = tid & 3;       // 0..3 float4 slot in 16-wide k tile
  const int m  = m0 + r;
  const int bX = m & 31;
  const int tl = m >> 5;
  const float* xrow = X + (bX * trows + t0 + tl) * K;
  const float* wrow = W + (n0 + r) * K;

  for (int kt = 0; kt < K; kt += 16) {
    float4 xv = *(const float4*)&xrow[kt + kq * 4];
    float4 wv = *(const float4*)&wrow[kt + kq * 4];
    Xs[kq * 4 + 0][r] = xv.x; Xs[kq * 4 + 1][r] = xv.y;
    Xs[kq * 4 + 2][r] = xv.z; Xs[kq * 4 + 3][r] = xv.w;
    Ws[kq * 4 + 0][r] = wv.x; Ws[kq * 4 + 1][r] = wv.y;
    Ws[kq * 4 + 2][r] = wv.z; Ws[kq * 4 + 3][r] = wv.w;
    __syncthreads();
#pragma unroll
    for (int k = 0; k < 16; ++k) {
      float4 xa = *(const float4*)&Xs[k][ty * 4];
      float4 wa = *(const float4*)&Ws[k][tx * 8];
      float4 wb = *(const float4*)&Ws[k][tx * 8 + 4];
      float xr[4] = {xa.x, xa.y, xa.z, xa.w};
      float wr[8] = {wa.x, wa.y, wa.z, wa.w, wb.x, wb.y, wb.z, wb.w};
#pragma unroll
      for (int i = 0; i < 4; ++i)
#pragma unroll
        for (int j = 0; j < 8; ++j)
          acc[i][j] = fmaf(xr[i], wr[j], acc[i][j]);
    }
    __syncthreads();
  }

  float bb[8];
#pragma unroll
  for (int j = 0; j < 8; ++j) {
    int n = n0 + tx * 8 + j;
    bb[j] = bia[n] + bib[n];
  }
#pragma unroll
  for (int i = 0; i < 4; ++i) {
    int mm = m0 + ty * 4 + i;
    int b = mm & 31, t = mm >> 5;
#pragma unroll
    for (int j = 0; j < 8; ++j) {
      int n = n0 + tx * 8 + j;
      xg[(t * G4 + n) * BATCH + b] = acc[i][j] + bb[j];
    }
  }
}

// =====================================================================
// Persistent LSTM scan over TC steps. 128 WGs x 256 threads.
// WG w owns h-columns {2w, 2w+1} (8 gate rows). Whh slice in LDS,
// h_{t-1} staged to LDS each step (PAD=260), c in registers of tid<64.
// Grid barrier per step: 2-level cumulative atomic counters + flag.
// =====================================================================
__global__ __launch_bounds__(256) void lstm_scan(
    const float* __restrict__ xg,    // [TC][G4][BATCH], biases folded in
    const float* __restrict__ Whh,   // [G4][HDIM]
    float* __restrict__ out,         // h output
    int trows_out, int t0_out,
    float* __restrict__ hbuf,        // [2][BATCH][HDIM]
    float* __restrict__ cbuf,        // [BATCH][HDIM]
    unsigned* __restrict__ ctr,      // 32 u32, zeroed before launch
    int nsteps)
{
  const int w   = blockIdx.x;        // 0..127
  const int tid = threadIdx.x;
  const int j0  = w * 2;

  __shared__ float h_lds[BATCH][260];  // padded: <=4-way conflict on b128
  __shared__ float w_lds[8][HDIM];     // row idx = g*2 + jl
  __shared__ float part[512];          // [dot][khalf], dot=(jl*4+g)*32+b
  __shared__ float xgv[8][BATCH];

  // preload Whh slice (rows: gate g, local col jl -> Whh[g*256 + j0 + jl])
#pragma unroll
  for (int rr = 0; rr < 8; ++rr) {
    int g = rr >> 1, jl = rr & 1;
    w_lds[rr][tid] = Whh[(g * HDIM + j0 + jl) * HDIM + tid];
  }

  // phase-1 role
  const int b  = tid & 31;
  const int g2 = (tid >> 5) & 1;   // gate pair {0,1} or {2,3}
  const int kh = (tid >> 6) & 1;   // k half
  const int jl = (tid >> 7);       // local h column
  const int r0 = 4 * g2 + jl;      // w_lds row for gate 2*g2
  const int r1 = 4 * g2 + 2 + jl;  // w_lds row for gate 2*g2+1

  // phase-2 role (tid<64): (b2, j2) cell state in register
  float c_reg = 0.f;
  if (tid < 64) c_reg = cbuf[(tid & 31) * HDIM + j0 + (tid >> 5)];

  int p = 0;
  for (int t = 0; t < nsteps; ++t) {
    // ---- stage h_{t-1} (coalesced) and this step's xg slice ----
    const float4* hp = (const float4*)(hbuf + p * (BATCH * HDIM));
#pragma unroll
    for (int q = 0; q < 8; ++q) {
      int f4 = q * 256 + tid;           // 0..2047
      float4 v = hp[f4];
      int bb2 = f4 >> 6, kq = f4 & 63;
      *(float4*)&h_lds[bb2][kq * 4] = v;
    }
    {
      int rr = tid >> 5, bb2 = tid & 31;
      int g = rr >> 1, jj = rr & 1;
      xgv[rr][bb2] = xg[(t * G4 + (g * HDIM + j0 + jj)) * BATCH + bb2];
    }
    __syncthreads();

    // ---- phase 1: partial dot products (2 gates, half k) ----
    float a0 = 0.f, a1 = 0.f;
    const float* hrow = &h_lds[b][kh * 128];
    const float* wr0  = &w_lds[r0][kh * 128];
    const float* wr1  = &w_lds[r1][kh * 128];
#pragma unroll
    for (int k = 0; k < 128; k += 4) {
      float4 hv = *(const float4*)&hrow[k];
      float4 w0 = *(const float4*)&wr0[k];
      float4 w1 = *(const float4*)&wr1[k];
      a0 = fmaf(hv.x, w0.x, a0); a0 = fmaf(hv.y, w0.y, a0);
      a0 = fmaf(hv.z, w0.z, a0); a0 = fmaf(hv.w, w0.w, a0);
      a1 = fmaf(hv.x, w1.x, a1); a1 = fmaf(hv.y, w1.y, a1);
      a1 = fmaf(hv.z, w1.z, a1); a1 = fmaf(hv.w, w1.w, a1);
    }
    if (kh == 0) { a0 += xgv[r0][b]; a1 += xgv[r1][b]; }
    {
      int dot0 = (jl * 4 + 2 * g2) * 32 + b;
      int dot1 = (jl * 4 + 2 * g2 + 1) * 32 + b;
      part[dot0 * 2 + kh] = a0;
      part[dot1 * 2 + kh] = a1;
    }
    __syncthreads();

    // ---- phase 2: gate nonlinearities + state update (64 threads) ----
    if (tid < 64) {
      int bb2 = tid & 31, jj = tid >> 5;
      float gv[4];
#pragma unroll
      for (int g = 0; g < 4; ++g) {
        int d = (jj * 4 + g) * 32 + bb2;
        gv[g] = part[d * 2] + part[d * 2 + 1];
      }
      float ig = 1.f / (1.f + __expf(-gv[0]));
      float fg = 1.f / (1.f + __expf(-gv[1]));
      float gg = tanhf(gv[2]);
      float og = 1.f / (1.f + __expf(-gv[3]));
      c_reg = fg * c_reg + ig * gg;
      float h = og * tanhf(c_reg);
      int j = j0 + jj;
      hbuf[(p ^ 1) * (BATCH * HDIM) + bb2 * HDIM + j] = h;
      out[(bb2 * trows_out + t0_out + t) * HDIM + j] = h;
    }
    __threadfence();   // make h stores visible device-wide (release)
    __syncthreads();

    // ---- grid barrier (cumulative 2-level counters) ----
    if (tid == 0) {
      unsigned target = (unsigned)(t + 1);
      unsigned grp = (unsigned)w >> 3;              // 16 groups of 8
      unsigned old = atomicAdd(&ctr[grp], 1u);
      if (old == 8u * target - 1u) {
        unsigned ro = atomicAdd(&ctr[16], 1u);
        if (ro == 16u * target - 1u) {
          __hip_atomic_store(&ctr[17], target, __ATOMIC_RELEASE,
                             __HIP_MEMORY_SCOPE_AGENT);
        }
      }
      while (__hip_atomic_load(&ctr[17], __ATOMIC_ACQUIRE,
                               __HIP_MEMORY_SCOPE_AGENT) < target) { }
    }
    __syncthreads();
    __threadfence();   // acquire: invalidate stale cached h before restage
    p ^= 1;
  }

  if (tid < 64) cbuf[(tid & 31) * HDIM + j0 + (tid >> 5)] = c_reg;
}

// =====================================================================
// Host launcher
// =====================================================================
extern "C" void kernel_launch(void* const* d_in, const int* in_sizes, int n_in,
                              void* d_out, int out_size, void* d_ws, size_t ws_size,
                              hipStream_t stream) {
  (void)in_sizes; (void)n_in; (void)out_size; (void)ws_size;
  const float* enc  = (const float*)d_in[0];
  const float* Wih0 = (const float*)d_in[1];
  const float* Whh0 = (const float*)d_in[2];
  const float* bih0 = (const float*)d_in[3];
  const float* bhh0 = (const float*)d_in[4];
  const float* Wih1 = (const float*)d_in[5];
  const float* Whh1 = (const float*)d_in[6];
  const float* bih1 = (const float*)d_in[7];
  const float* bhh1 = (const float*)d_in[8];
  float* out = (float*)d_out;

  // workspace layout (floats)
  float* ws  = (float*)d_ws;
  float* xg  = ws;                     // TC*G4*BATCH        = 4,194,304
  float* h1  = ws + 4194304;           // BATCH*TC*HDIM      = 1,048,576
  float* st  = ws + 5242880;           // state region below (zeroed each call)
  float* hb0 = st;                     // 2*BATCH*HDIM = 16384
  float* cb0 = st + 16384;             // 8192
  float* hb1 = st + 24576;             // 16384
  float* cb1 = st + 40960;             // 8192
  unsigned* ctrs = (unsigned*)(st + 49152);  // 16 launches * 32 u32

  hipMemsetAsync(st, 0, (size_t)(49152 + 512) * 4, stream);

  for (int ch = 0; ch < 8; ++ch) {
    // layer 0: xg = enc . Wih0^T + b   (K=512, X rows span full T)
    gemm_xg<<<dim3(32, 8), 512, 0, stream>>>(enc, Wih0, bih0, bhh0, xg,
                                             512, TFULL, ch * TC);
    lstm_scan<<<NWG, 256, 0, stream>>>(xg, Whh0, h1, TC, 0,
                                       hb0, cb0, ctrs + (ch * 2 + 0) * 32, TC);
    // layer 1: xg = h1 . Wih1^T + b   (K=256, X rows chunk-local)
    gemm_xg<<<dim3(32, 8), 512, 0, stream>>>(h1, Wih1, bih1, bhh1, xg,
                                             256, TC, 0);
    lstm_scan<<<NWG, 256, 0, stream>>>(xg, Whh1, out, TFULL, ch * TC,
                                       hb1, cb1, ctrs + (ch * 2 + 1) * 32, TC);
  }
}

// Round 2
// 14206.337 us; speedup vs baseline: 4.2732x; 4.2732x over previous
//
#include <hip/hip_runtime.h>

// Problem constants
#define BATCH 32
#define TFULL 1024
#define HDIM  256
#define G4    1024   // 4*HDIM
#define TC    128    // timestep chunk
#define NWG   128    // scan workgroups (co-resident on 256 CUs)

// =====================================================================
// GEMM: xg[tl][n][b] = sum_k X[b, t0+tl, k] * W[n, k] + bia[n] + bib[n]
// Logical row m = tl*32 + b, m in [0, 4096). Tile 128x128, 512 threads,
// per-thread 4x8. K in {512, 256}, multiples of 16.
// =====================================================================
__global__ __launch_bounds__(512) void gemm_xg(
    const float* __restrict__ X, const float* __restrict__ W,
    const float* __restrict__ bia, const float* __restrict__ bib,
    float* __restrict__ xg, int K, int trows, int t0)
{
  __shared__ float Xs[16][128];
  __shared__ float Ws[16][128];
  const int tid = threadIdx.x;
  const int m0 = blockIdx.x * 128;
  const int n0 = blockIdx.y * 128;
  const int tx = tid & 15;      // n-dim: 8 cols each
  const int ty = tid >> 4;      // m-dim: 4 rows each (0..31)

  float acc[4][8];
#pragma unroll
  for (int i = 0; i < 4; ++i)
#pragma unroll
    for (int j = 0; j < 8; ++j) acc[i][j] = 0.f;

  const int r  = tid >> 2;      // 0..127 tile row
  const int kq = tid & 3;       // 0..3 float4 slot in 16-wide k tile
  const int m  = m0 + r;
  const int bX = m & 31;
  const int tl = m >> 5;
  const float* xrow = X + (bX * trows + t0 + tl) * K;
  const float* wrow = W + (n0 + r) * K;

  for (int kt = 0; kt < K; kt += 16) {
    float4 xv = *(const float4*)&xrow[kt + kq * 4];
    float4 wv = *(const float4*)&wrow[kt + kq * 4];
    Xs[kq * 4 + 0][r] = xv.x; Xs[kq * 4 + 1][r] = xv.y;
    Xs[kq * 4 + 2][r] = xv.z; Xs[kq * 4 + 3][r] = xv.w;
    Ws[kq * 4 + 0][r] = wv.x; Ws[kq * 4 + 1][r] = wv.y;
    Ws[kq * 4 + 2][r] = wv.z; Ws[kq * 4 + 3][r] = wv.w;
    __syncthreads();
#pragma unroll
    for (int k = 0; k < 16; ++k) {
      float4 xa = *(const float4*)&Xs[k][ty * 4];
      float4 wa = *(const float4*)&Ws[k][tx * 8];
      float4 wb = *(const float4*)&Ws[k][tx * 8 + 4];
      float xr[4] = {xa.x, xa.y, xa.z, xa.w};
      float wr[8] = {wa.x, wa.y, wa.z, wa.w, wb.x, wb.y, wb.z, wb.w};
#pragma unroll
      for (int i = 0; i < 4; ++i)
#pragma unroll
        for (int j = 0; j < 8; ++j)
          acc[i][j] = fmaf(xr[i], wr[j], acc[i][j]);
    }
    __syncthreads();
  }

  float bb[8];
#pragma unroll
  for (int j = 0; j < 8; ++j) {
    int n = n0 + tx * 8 + j;
    bb[j] = bia[n] + bib[n];
  }
#pragma unroll
  for (int i = 0; i < 4; ++i) {
    int mm = m0 + ty * 4 + i;
    int b = mm & 31, t = mm >> 5;
#pragma unroll
    for (int j = 0; j < 8; ++j) {
      int n = n0 + tx * 8 + j;
      xg[(t * G4 + n) * BATCH + b] = acc[i][j] + bb[j];
    }
  }
}

// =====================================================================
// Persistent LSTM scan over TC steps. 128 WGs x 256 threads.
// h exchanged through a coherent-point (MALL) mailbox:
//   writers: sc1 relaxed-agent atomic stores, then s_waitcnt vmcnt(0),
//            then per-WG sequence flag (relaxed agent store, no RMW).
//   readers: poll 128 flags (relaxed agent loads), then sc0/sc1 bulk
//            loads of h. No fences -> L2 stays warm (weights, xg).
// =====================================================================
__global__ __launch_bounds__(256) void lstm_scan(
    const float* __restrict__ xg,    // [TC][G4][BATCH], biases folded in
    const float* __restrict__ Whh,   // [G4][HDIM]
    float* __restrict__ out,         // h output
    int trows_out, int t0_out,
    float* __restrict__ hbuf,        // [2][BATCH][HDIM] mailbox
    float* __restrict__ cbuf,        // [BATCH][HDIM]
    unsigned* __restrict__ flags,    // NWG u32, zeroed before launch
    int nsteps)
{
  const int w   = blockIdx.x;        // 0..127
  const int tid = threadIdx.x;
  const int j0  = w * 2;

  __shared__ float h_lds[BATCH][260];
  __shared__ float w_lds[8][HDIM];     // row idx = g*2 + jl
  __shared__ float part[1024];         // [dot][khalf]
  __shared__ float xgv[8][BATCH];

#pragma unroll
  for (int rr = 0; rr < 8; ++rr) {
    int g = rr >> 1, jl = rr & 1;
    w_lds[rr][tid] = Whh[(g * HDIM + j0 + jl) * HDIM + tid];
  }

  const int b  = tid & 31;
  const int g2 = (tid >> 5) & 1;   // gate pair {0,1} or {2,3}
  const int kh = (tid >> 6) & 1;   // k half
  const int jl = (tid >> 7);       // local h column
  const int r0 = 4 * g2 + jl;
  const int r1 = 4 * g2 + 2 + jl;

  float c_reg = 0.f;
  if (tid < 64) c_reg = cbuf[(tid & 31) * HDIM + j0 + (tid >> 5)];

  int p = 0;
  for (int t = 0; t < nsteps; ++t) {
    // ---- wait until all WGs finished step t-1 (flag >= t) ----
    if (t > 0 && tid < 64) {
      const unsigned tgt = (unsigned)t;
      for (;;) {
        unsigned f0 = __hip_atomic_load(&flags[tid], __ATOMIC_RELAXED,
                                        __HIP_MEMORY_SCOPE_AGENT);
        unsigned f1 = __hip_atomic_load(&flags[tid + 64], __ATOMIC_RELAXED,
                                        __HIP_MEMORY_SCOPE_AGENT);
        if (__all(f0 >= tgt && f1 >= tgt)) break;
      }
    }
    __syncthreads();

    // ---- stage h_{t-1} from mailbox (cache-bypassing loads) ----
    const float4* hp = (const float4*)(hbuf + p * (BATCH * HDIM));
    float4 hv[8];
#pragma unroll
    for (int q = 0; q < 8; ++q) {
      const float4* ap = hp + q * 256 + tid;
      asm volatile("global_load_dwordx4 %0, %1, off sc0 sc1"
                   : "=v"(hv[q]) : "v"(ap));
    }
    {
      int rr = tid >> 5, bb2 = tid & 31;
      int g = rr >> 1, jj = rr & 1;
      xgv[rr][bb2] = xg[(t * G4 + (g * HDIM + j0 + jj)) * BATCH + bb2];
    }
    asm volatile("s_waitcnt vmcnt(0)" ::: "memory");
#pragma unroll
    for (int q = 0; q < 8; ++q) {
      int f4 = q * 256 + tid;
      int bb2 = f4 >> 6, kq = f4 & 63;
      *(float4*)&h_lds[bb2][kq * 4] = hv[q];
    }
    __syncthreads();

    // ---- phase 1: partial dot products (2 gates, half k) ----
    float a0 = 0.f, a1 = 0.f;
    const float* hrow = &h_lds[b][kh * 128];
    const float* wr0  = &w_lds[r0][kh * 128];
    const float* wr1  = &w_lds[r1][kh * 128];
#pragma unroll
    for (int k = 0; k < 128; k += 4) {
      float4 hvv = *(const float4*)&hrow[k];
      float4 w0 = *(const float4*)&wr0[k];
      float4 w1 = *(const float4*)&wr1[k];
      a0 = fmaf(hvv.x, w0.x, a0); a0 = fmaf(hvv.y, w0.y, a0);
      a0 = fmaf(hvv.z, w0.z, a0); a0 = fmaf(hvv.w, w0.w, a0);
      a1 = fmaf(hvv.x, w1.x, a1); a1 = fmaf(hvv.y, w1.y, a1);
      a1 = fmaf(hvv.z, w1.z, a1); a1 = fmaf(hvv.w, w1.w, a1);
    }
    if (kh == 0) { a0 += xgv[r0][b]; a1 += xgv[r1][b]; }
    {
      int dot0 = (jl * 4 + 2 * g2) * 32 + b;
      int dot1 = (jl * 4 + 2 * g2 + 1) * 32 + b;
      part[dot0 * 2 + kh] = a0;
      part[dot1 * 2 + kh] = a1;
    }
    __syncthreads();

    // ---- phase 2: gates + state update + mailbox publish ----
    if (tid < 64) {
      int bb2 = tid & 31, jj = tid >> 5;
      float gv[4];
#pragma unroll
      for (int g = 0; g < 4; ++g) {
        int d = (jj * 4 + g) * 32 + bb2;
        gv[g] = part[d * 2] + part[d * 2 + 1];
      }
      float ig = 1.f / (1.f + __expf(-gv[0]));
      float fg = 1.f / (1.f + __expf(-gv[1]));
      float gg = tanhf(gv[2]);
      float og = 1.f / (1.f + __expf(-gv[3]));
      c_reg = fg * c_reg + ig * gg;
      float h = og * tanhf(c_reg);
      int j = j0 + jj;
      out[(bb2 * trows_out + t0_out + t) * HDIM + j] = h;
      __hip_atomic_store(&hbuf[(p ^ 1) * (BATCH * HDIM) + bb2 * HDIM + j], h,
                         __ATOMIC_RELAXED, __HIP_MEMORY_SCOPE_AGENT);
      asm volatile("s_waitcnt vmcnt(0)" ::: "memory");
      if (tid == 0)
        __hip_atomic_store(&flags[w], (unsigned)(t + 1), __ATOMIC_RELAXED,
                           __HIP_MEMORY_SCOPE_AGENT);
    }
    p ^= 1;
  }

  if (tid < 64) cbuf[(tid & 31) * HDIM + j0 + (tid >> 5)] = c_reg;
}

// =====================================================================
// Host launcher
// =====================================================================
extern "C" void kernel_launch(void* const* d_in, const int* in_sizes, int n_in,
                              void* d_out, int out_size, void* d_ws, size_t ws_size,
                              hipStream_t stream) {
  (void)in_sizes; (void)n_in; (void)out_size; (void)ws_size;
  const float* enc  = (const float*)d_in[0];
  const float* Wih0 = (const float*)d_in[1];
  const float* Whh0 = (const float*)d_in[2];
  const float* bih0 = (const float*)d_in[3];
  const float* bhh0 = (const float*)d_in[4];
  const float* Wih1 = (const float*)d_in[5];
  const float* Whh1 = (const float*)d_in[6];
  const float* bih1 = (const float*)d_in[7];
  const float* bhh1 = (const float*)d_in[8];
  float* out = (float*)d_out;

  // workspace layout (floats)
  float* ws  = (float*)d_ws;
  float* xg  = ws;                     // TC*G4*BATCH        = 4,194,304
  float* h1  = ws + 4194304;           // BATCH*TC*HDIM      = 1,048,576
  float* st  = ws + 5242880;           // zeroed state region
  float* hb0 = st;                     // 2*BATCH*HDIM = 16384
  float* cb0 = st + 16384;             // 8192
  float* hb1 = st + 24576;             // 16384
  float* cb1 = st + 40960;             // 8192
  unsigned* flg = (unsigned*)(st + 49152);   // 16 dispatches * NWG u32

  hipMemsetAsync(st, 0, (size_t)(49152 + 16 * NWG) * 4, stream);

  for (int ch = 0; ch < 8; ++ch) {
    gemm_xg<<<dim3(32, 8), 512, 0, stream>>>(enc, Wih0, bih0, bhh0, xg,
                                             512, TFULL, ch * TC);
    lstm_scan<<<NWG, 256, 0, stream>>>(xg, Whh0, h1, TC, 0,
                                       hb0, cb0, flg + (ch * 2 + 0) * NWG, TC);
    gemm_xg<<<dim3(32, 8), 512, 0, stream>>>(h1, Wih1, bih1, bhh1, xg,
                                             256, TC, 0);
    lstm_scan<<<NWG, 256, 0, stream>>>(xg, Whh1, out, TFULL, ch * TC,
                                       hb1, cb1, flg + (ch * 2 + 1) * NWG, TC);
  }
}

// Round 3
// 7867.127 us; speedup vs baseline: 7.7165x; 1.8058x over previous
//
#include <hip/hip_runtime.h>

// Problem constants
#define BATCH 32
#define TFULL 1024
#define HDIM  256
#define G4    1024   // 4*HDIM
#define TC    128    // timestep chunk
#define NWG   256    // scan workgroups: 32 samples x 8 roles, 1 per CU

// =====================================================================
// GEMM: xg[tl][b][n] = sum_k X[b, t0+tl, k] * W[n, k] + bia[n] + bib[n]
// (n-contiguous layout so the scan reads one coalesced line per step)
// =====================================================================
__global__ __launch_bounds__(512) void gemm_xg(
    const float* __restrict__ X, const float* __restrict__ W,
    const float* __restrict__ bia, const float* __restrict__ bib,
    float* __restrict__ xg, int K, int trows, int t0)
{
  __shared__ float Xs[16][128];
  __shared__ float Ws[16][128];
  const int tid = threadIdx.x;
  const int m0 = blockIdx.x * 128;
  const int n0 = blockIdx.y * 128;
  const int tx = tid & 15;      // n-dim: 8 cols each
  const int ty = tid >> 4;      // m-dim: 4 rows each

  float acc[4][8];
#pragma unroll
  for (int i = 0; i < 4; ++i)
#pragma unroll
    for (int j = 0; j < 8; ++j) acc[i][j] = 0.f;

  const int r  = tid >> 2;
  const int kq = tid & 3;
  const int m  = m0 + r;
  const int bX = m & 31;
  const int tl = m >> 5;
  const float* xrow = X + (bX * trows + t0 + tl) * K;
  const float* wrow = W + (n0 + r) * K;

  for (int kt = 0; kt < K; kt += 16) {
    float4 xv = *(const float4*)&xrow[kt + kq * 4];
    float4 wv = *(const float4*)&wrow[kt + kq * 4];
    Xs[kq * 4 + 0][r] = xv.x; Xs[kq * 4 + 1][r] = xv.y;
    Xs[kq * 4 + 2][r] = xv.z; Xs[kq * 4 + 3][r] = xv.w;
    Ws[kq * 4 + 0][r] = wv.x; Ws[kq * 4 + 1][r] = wv.y;
    Ws[kq * 4 + 2][r] = wv.z; Ws[kq * 4 + 3][r] = wv.w;
    __syncthreads();
#pragma unroll
    for (int k = 0; k < 16; ++k) {
      float4 xa = *(const float4*)&Xs[k][ty * 4];
      float4 wa = *(const float4*)&Ws[k][tx * 8];
      float4 wb = *(const float4*)&Ws[k][tx * 8 + 4];
      float xr[4] = {xa.x, xa.y, xa.z, xa.w};
      float wr[8] = {wa.x, wa.y, wa.z, wa.w, wb.x, wb.y, wb.z, wb.w};
#pragma unroll
      for (int i = 0; i < 4; ++i)
#pragma unroll
        for (int j = 0; j < 8; ++j)
          acc[i][j] = fmaf(xr[i], wr[j], acc[i][j]);
    }
    __syncthreads();
  }

  float bb[8];
#pragma unroll
  for (int j = 0; j < 8; ++j) {
    int n = n0 + tx * 8 + j;
    bb[j] = bia[n] + bib[n];
  }
#pragma unroll
  for (int i = 0; i < 4; ++i) {
    int mm = m0 + ty * 4 + i;
    int b = mm & 31, t = mm >> 5;
    float* dst = &xg[(size_t)(t * BATCH + b) * G4 + n0 + tx * 8];
    float4 v0 = make_float4(acc[i][0] + bb[0], acc[i][1] + bb[1],
                            acc[i][2] + bb[2], acc[i][3] + bb[3]);
    float4 v1 = make_float4(acc[i][4] + bb[4], acc[i][5] + bb[5],
                            acc[i][6] + bb[6], acc[i][7] + bb[7]);
    *(float4*)dst = v0;
    *(float4*)(dst + 4) = v1;
  }
}

// =====================================================================
// Persistent per-sample LSTM scan. 256 WGs x 256 threads, 1 WG/CU
// (forced by LDS pad -> co-residency guaranteed: 256 WGs on 256 CUs).
// WG w: sample s = w>>3, role r = w&7 -> owns h columns [r*32, r*32+32)
// i.e. gate rows {gt*256 + r*32 + jl}. Whh slice lives in VGPRs
// (128 floats/thread). Per step: poll 8 flags (1 line), load 1 KB h,
// 128 FMA/thread, publish 128 B + flag. All exchange via MALL
// (sc0 sc1 loads / agent-scope relaxed atomic stores, vmcnt-ordered).
// =====================================================================
__global__ __launch_bounds__(256, 1) void lstm_scan(
    const float* __restrict__ xg,    // [TC][BATCH][G4], biases folded
    const float* __restrict__ Whh,   // [G4][HDIM]
    float* __restrict__ out,         // h output [B][trows_out][HDIM]
    int trows_out, int t0_out,
    float* __restrict__ hmb,         // [S][2][HDIM] mailboxes
    float* __restrict__ cbuf,        // [S][HDIM]
    unsigned* __restrict__ flags,    // [S][8], zeroed
    int nsteps)
{
  const int w   = blockIdx.x;
  const int tid = threadIdx.x;
  const int s   = w >> 3;
  const int r   = w & 7;
  const int gt  = tid >> 6;        // gate type = wave id
  const int jl  = (tid >> 1) & 31; // local column
  const int kh  = tid & 1;         // k half
  const int n   = gt * 256 + r * 32 + jl;

  __shared__ float h_lds[HDIM];
  __shared__ float part[128];          // [gt][jl]
  __shared__ float pad_force[21504];   // 84 KB -> 1 WG/CU
  if (nsteps < 0) pad_force[tid] = 0.f;  // keep alive, never runs

  // ---- load my 128 weight floats into VGPRs (constant across steps) ----
  float4 wv[32];
  {
    const float4* wrow = (const float4*)(Whh + n * HDIM + kh * 128);
#pragma unroll
    for (int q = 0; q < 32; ++q) wv[q] = wrow[q];
  }

  float c_reg = 0.f;
  if (tid < 32) c_reg = cbuf[s * HDIM + r * 32 + tid];

  float* mb = hmb + s * 2 * HDIM;
  unsigned* fl = flags + s * 8;

  int p = 0;
  for (int t = 0; t < nsteps; ++t) {
    // prefetch this step's gate bias (independent of h -> overlaps poll)
    float xv = xg[((size_t)(t * BATCH + s) << 10) + n];

    // ---- wait for all 8 roles of my sample to finish step t-1 ----
    if (t > 0 && tid < 64) {
      const unsigned tgt = (unsigned)t;
      for (;;) {
        unsigned f = __hip_atomic_load(&fl[tid & 7], __ATOMIC_RELAXED,
                                       __HIP_MEMORY_SCOPE_AGENT);
        if (__all(f >= tgt)) break;
      }
    }
    __syncthreads();

    // ---- wave 0 loads h_{t-1} (1 KB) from mailbox, stages to LDS ----
    if (tid < 64) {
      float4 hv;
      const float4* hp = (const float4*)(mb + p * HDIM) + tid;
      asm volatile("global_load_dwordx4 %0, %1, off sc0 sc1"
                   : "=v"(hv) : "v"(hp));
      asm volatile("s_waitcnt vmcnt(0)" ::: "memory");
      *(float4*)&h_lds[tid * 4] = hv;
    }
    __syncthreads();

    // ---- dot: gate[n] partial over my k-half (broadcast LDS reads) ----
    const float4* hrow = (const float4*)&h_lds[kh * 128];
    float a0 = 0.f, a1 = 0.f, a2 = 0.f, a3 = 0.f;
#pragma unroll
    for (int q = 0; q < 32; q += 4) {
      float4 h0 = hrow[q + 0], h1 = hrow[q + 1];
      float4 h2 = hrow[q + 2], h3 = hrow[q + 3];
      a0 = fmaf(wv[q+0].x, h0.x, a0); a0 = fmaf(wv[q+0].y, h0.y, a0);
      a0 = fmaf(wv[q+0].z, h0.z, a0); a0 = fmaf(wv[q+0].w, h0.w, a0);
      a1 = fmaf(wv[q+1].x, h1.x, a1); a1 = fmaf(wv[q+1].y, h1.y, a1);
      a1 = fmaf(wv[q+1].z, h1.z, a1); a1 = fmaf(wv[q+1].w, h1.w, a1);
      a2 = fmaf(wv[q+2].x, h2.x, a2); a2 = fmaf(wv[q+2].y, h2.y, a2);
      a2 = fmaf(wv[q+2].z, h2.z, a2); a2 = fmaf(wv[q+2].w, h2.w, a2);
      a3 = fmaf(wv[q+3].x, h3.x, a3); a3 = fmaf(wv[q+3].y, h3.y, a3);
      a3 = fmaf(wv[q+3].z, h3.z, a3); a3 = fmaf(wv[q+3].w, h3.w, a3);
    }
    float a = (a0 + a1) + (a2 + a3);
    a += __shfl_xor(a, 1);              // combine k-halves (lane pair)
    if (kh == 0) part[gt * 32 + jl] = a + xv;
    __syncthreads();

    // ---- gates -> c,h update -> publish (32 threads) ----
    if (tid < 32) {
      float gi = part[tid], gf = part[32 + tid];
      float gg = part[64 + tid], go = part[96 + tid];
      float ig = 1.f / (1.f + __expf(-gi));
      float fg = 1.f / (1.f + __expf(-gf));
      float g  = tanhf(gg);
      float og = 1.f / (1.f + __expf(-go));
      c_reg = fg * c_reg + ig * g;
      float h = og * tanhf(c_reg);
      __hip_atomic_store(&mb[(p ^ 1) * HDIM + r * 32 + tid], h,
                         __ATOMIC_RELAXED, __HIP_MEMORY_SCOPE_AGENT);
      asm volatile("s_waitcnt vmcnt(0)" ::: "memory");
      if (tid == 0)
        __hip_atomic_store(&fl[r], (unsigned)(t + 1), __ATOMIC_RELAXED,
                           __HIP_MEMORY_SCOPE_AGENT);
      // output store off the critical path (after flag publish)
      out[((size_t)s * trows_out + t0_out + t) * HDIM + r * 32 + tid] = h;
    }
    p ^= 1;
  }

  if (tid < 32) cbuf[s * HDIM + r * 32 + tid] = c_reg;
}

// =====================================================================
// Host launcher
// =====================================================================
extern "C" void kernel_launch(void* const* d_in, const int* in_sizes, int n_in,
                              void* d_out, int out_size, void* d_ws, size_t ws_size,
                              hipStream_t stream) {
  (void)in_sizes; (void)n_in; (void)out_size; (void)ws_size;
  const float* enc  = (const float*)d_in[0];
  const float* Wih0 = (const float*)d_in[1];
  const float* Whh0 = (const float*)d_in[2];
  const float* bih0 = (const float*)d_in[3];
  const float* bhh0 = (const float*)d_in[4];
  const float* Wih1 = (const float*)d_in[5];
  const float* Whh1 = (const float*)d_in[6];
  const float* bih1 = (const float*)d_in[7];
  const float* bhh1 = (const float*)d_in[8];
  float* out = (float*)d_out;

  // workspace layout (floats)
  float* ws  = (float*)d_ws;
  float* xg  = ws;                     // TC*BATCH*G4 = 4,194,304
  float* h1  = ws + 4194304;           // BATCH*TC*HDIM = 1,048,576
  float* st  = ws + 5242880;           // zeroed state region
  float* hb0 = st;                     // 32*2*256 = 16384
  float* cb0 = st + 16384;             // 8192
  float* hb1 = st + 24576;             // 16384
  float* cb1 = st + 40960;             // 8192
  unsigned* flg = (unsigned*)(st + 49152);   // 16 dispatches * 32*8 u32

  hipMemsetAsync(st, 0, (size_t)(49152 + 16 * 256) * 4, stream);

  for (int ch = 0; ch < 8; ++ch) {
    gemm_xg<<<dim3(32, 8), 512, 0, stream>>>(enc, Wih0, bih0, bhh0, xg,
                                             512, TFULL, ch * TC);
    lstm_scan<<<NWG, 256, 0, stream>>>(xg, Whh0, h1, TC, 0,
                                       hb0, cb0, flg + (ch * 2 + 0) * 256, TC);
    gemm_xg<<<dim3(32, 8), 512, 0, stream>>>(h1, Wih1, bih1, bhh1, xg,
                                             256, TC, 0);
    lstm_scan<<<NWG, 256, 0, stream>>>(xg, Whh1, out, TFULL, ch * TC,
                                       hb1, cb1, flg + (ch * 2 + 1) * 256, TC);
  }
}

// Round 5
// 4205.822 us; speedup vs baseline: 14.4340x; 1.8705x over previous
//
#include <hip/hip_runtime.h>

// Problem constants
#define BATCH 32
#define TFULL 1024
#define HDIM  256
#define G4    1024   // 4*HDIM
#define TC    128    // timestep chunk
#define NWG   256    // scan workgroups: 32 samples x 8 roles

// =====================================================================
// GEMM: xg[tl][b][n] = sum_k X[b, t0+tl, k] * W[n, k] + bia[n] + bib[n]
// =====================================================================
__global__ __launch_bounds__(512) void gemm_xg(
    const float* __restrict__ X, const float* __restrict__ W,
    const float* __restrict__ bia, const float* __restrict__ bib,
    float* __restrict__ xg, int K, int trows, int t0)
{
  __shared__ float Xs[16][128];
  __shared__ float Ws[16][128];
  const int tid = threadIdx.x;
  const int m0 = blockIdx.x * 128;
  const int n0 = blockIdx.y * 128;
  const int tx = tid & 15;
  const int ty = tid >> 4;

  float acc[4][8];
#pragma unroll
  for (int i = 0; i < 4; ++i)
#pragma unroll
    for (int j = 0; j < 8; ++j) acc[i][j] = 0.f;

  const int r  = tid >> 2;
  const int kq = tid & 3;
  const int m  = m0 + r;
  const int bX = m & 31;
  const int tl = m >> 5;
  const float* xrow = X + (bX * trows + t0 + tl) * K;
  const float* wrow = W + (n0 + r) * K;

  for (int kt = 0; kt < K; kt += 16) {
    float4 xv = *(const float4*)&xrow[kt + kq * 4];
    float4 wv = *(const float4*)&wrow[kt + kq * 4];
    Xs[kq * 4 + 0][r] = xv.x; Xs[kq * 4 + 1][r] = xv.y;
    Xs[kq * 4 + 2][r] = xv.z; Xs[kq * 4 + 3][r] = xv.w;
    Ws[kq * 4 + 0][r] = wv.x; Ws[kq * 4 + 1][r] = wv.y;
    Ws[kq * 4 + 2][r] = wv.z; Ws[kq * 4 + 3][r] = wv.w;
    __syncthreads();
#pragma unroll
    for (int k = 0; k < 16; ++k) {
      float4 xa = *(const float4*)&Xs[k][ty * 4];
      float4 wa = *(const float4*)&Ws[k][tx * 8];
      float4 wb = *(const float4*)&Ws[k][tx * 8 + 4];
      float xr[4] = {xa.x, xa.y, xa.z, xa.w};
      float wr[8] = {wa.x, wa.y, wa.z, wa.w, wb.x, wb.y, wb.z, wb.w};
#pragma unroll
      for (int i = 0; i < 4; ++i)
#pragma unroll
        for (int j = 0; j < 8; ++j)
          acc[i][j] = fmaf(xr[i], wr[j], acc[i][j]);
    }
    __syncthreads();
  }

  float bb[8];
#pragma unroll
  for (int j = 0; j < 8; ++j) {
    int n = n0 + tx * 8 + j;
    bb[j] = bia[n] + bib[n];
  }
#pragma unroll
  for (int i = 0; i < 4; ++i) {
    int mm = m0 + ty * 4 + i;
    int b = mm & 31, t = mm >> 5;
    float* dst = &xg[(size_t)(t * BATCH + b) * G4 + n0 + tx * 8];
    float4 v0 = make_float4(acc[i][0] + bb[0], acc[i][1] + bb[1],
                            acc[i][2] + bb[2], acc[i][3] + bb[3]);
    float4 v1 = make_float4(acc[i][4] + bb[4], acc[i][5] + bb[5],
                            acc[i][6] + bb[6], acc[i][7] + bb[7]);
    *(float4*)dst = v0;
    *(float4*)(dst + 4) = v1;
  }
}

// =====================================================================
// Persistent per-sample LSTM scan. 256 WGs (32 samples x 8 roles),
// 1 WG/CU forced by LDS pad. All exchange at the MALL (sc0 sc1).
//
// Tag-in-data mailbox: version v (global step count) of h is stored as
// 256 (h, v) pairs (8B atomic stores) in ring slot v&7. Readers poll
// the pairs themselves until all tags == v; the data arrives with the
// poll (one MALL round trip, no separate flag). Ring reuse is safe:
// a role reaches version v+8 only after reading v+7 complete, which
// transitively requires every role to have consumed version v.
// Version base continues across chunk dispatches (memset => version 0).
// Whh slice is pinned in VGPRs via asm loads (no rematerialization).
// =====================================================================
__global__ __launch_bounds__(256, 1) void lstm_scan(
    const float* __restrict__ xg,    // [TC][BATCH][G4], biases folded
    const float* __restrict__ Whh,   // [G4][HDIM]
    float* __restrict__ out,         // [B][trows_out][HDIM]
    int trows_out, int t0_out,
    float* __restrict__ hmb,         // [S][8 slots][256 pairs][2]
    float* __restrict__ cbuf,        // [S][HDIM]
    int vbase, int nsteps)
{
  const int w   = blockIdx.x;
  const int tid = threadIdx.x;
  const int s   = w & 31;           // sample
  const int r   = w >> 5;           // role: h columns [r*32, r*32+32)
  const int gt   = tid >> 6;        // gate type = wave id
  const int lane = tid & 63;
  const int jl   = lane & 31;       // local column
  const int kh   = lane >> 5;       // k half = wave half (broadcast-clean)
  const int n    = gt * 256 + r * 32 + jl;

  __shared__ float h_lds[HDIM];
  __shared__ float part[128];          // [gt][jl]
  __shared__ float pad_force[21504];   // 84 KB -> 1 WG/CU
  if (nsteps < 0) pad_force[tid] = 0.f;  // keep alive, never runs

  // ---- pin my 128 weight floats in VGPRs (asm: cannot rematerialize) ----
  float4 wv[32];
  {
    const float4* wrow = (const float4*)(Whh + n * HDIM + kh * 128);
#pragma unroll
    for (int q = 0; q < 32; ++q) {
      const float4* ap = wrow + q;
      asm volatile("global_load_dwordx4 %0, %1, off" : "=v"(wv[q]) : "v"(ap));
    }
    asm volatile("s_waitcnt vmcnt(0)" ::: "memory");
  }

  float c_reg = 0.f;
  if (tid < 32) c_reg = cbuf[s * HDIM + r * 32 + tid];

  float* mbx = hmb + (size_t)s * 8 * 512;   // 8 slots x 512 floats

  for (int t = 0; t < nsteps; ++t) {
    const unsigned g = (unsigned)(vbase + t);     // version we consume
    // prefetch this step's gate bias (independent of h -> overlaps poll)
    float xv = xg[((size_t)(t * BATCH + s) << 10) + n];

    // ---- wave 0: poll (h, tag) pairs of version g; data rides along ----
    if (tid < 64) {
      const float4* sp = (const float4*)(mbx + (size_t)(g & 7) * 512) + tid * 2;
      const float4* sp2 = sp + 1;
      float4 A, B;
      for (;;) {
        asm volatile(
            "global_load_dwordx4 %0, %2, off sc0 sc1\n\t"
            "global_load_dwordx4 %1, %3, off sc0 sc1\n\t"
            "s_waitcnt vmcnt(0)"
            : "=&v"(A), "=&v"(B) : "v"(sp), "v"(sp2) : "memory");
        bool ok = (__float_as_uint(A.y) == g) && (__float_as_uint(A.w) == g) &&
                  (__float_as_uint(B.y) == g) && (__float_as_uint(B.w) == g);
        if (__all(ok)) break;
      }
      *(float4*)&h_lds[tid * 4] = make_float4(A.x, A.z, B.x, B.z);
    }
    __syncthreads();   // sync#1: h_lds ready (also guards part[] reuse)

    // ---- dot over my k-half: pure-broadcast LDS reads, reg weights ----
    const float4* hrow = (const float4*)&h_lds[kh * 128];
    float a0 = 0.f, a1 = 0.f, a2 = 0.f, a3 = 0.f;
#pragma unroll
    for (int q = 0; q < 32; q += 4) {
      float4 h0 = hrow[q + 0], h1 = hrow[q + 1];
      float4 h2 = hrow[q + 2], h3 = hrow[q + 3];
      a0 = fmaf(wv[q+0].x, h0.x, a0); a0 = fmaf(wv[q+0].y, h0.y, a0);
      a0 = fmaf(wv[q+0].z, h0.z, a0); a0 = fmaf(wv[q+0].w, h0.w, a0);
      a1 = fmaf(wv[q+1].x, h1.x, a1); a1 = fmaf(wv[q+1].y, h1.y, a1);
      a1 = fmaf(wv[q+1].z, h1.z, a1); a1 = fmaf(wv[q+1].w, h1.w, a1);
      a2 = fmaf(wv[q+2].x, h2.x, a2); a2 = fmaf(wv[q+2].y, h2.y, a2);
      a2 = fmaf(wv[q+2].z, h2.z, a2); a2 = fmaf(wv[q+2].w, h2.w, a2);
      a3 = fmaf(wv[q+3].x, h3.x, a3); a3 = fmaf(wv[q+3].y, h3.y, a3);
      a3 = fmaf(wv[q+3].z, h3.z, a3); a3 = fmaf(wv[q+3].w, h3.w, a3);
    }
    float a = (a0 + a1) + (a2 + a3);
    a += __shfl_xor(a, 32);              // combine k-halves
    if (kh == 0) part[gt * 32 + jl] = a + xv;
    __syncthreads();   // sync#2: part ready

    // ---- gates -> c,h update -> publish pair (h, g+1) ----
    if (tid < 32) {
      float gi = part[tid], gf = part[32 + tid];
      float gg = part[64 + tid], go = part[96 + tid];
      float ig = 1.f / (1.f + __expf(-gi));
      float fg = 1.f / (1.f + __expf(-gf));
      float gv = tanhf(gg);
      float og = 1.f / (1.f + __expf(-go));
      c_reg = fg * c_reg + ig * gv;
      float h = og * tanhf(c_reg);
      float2 pv; pv.x = h; pv.y = __uint_as_float(g + 1u);
      float* pp = mbx + (size_t)((g + 1u) & 7) * 512 + (r * 32 + tid) * 2;
      asm volatile("global_store_dwordx2 %0, %1, off sc0 sc1"
                   :: "v"(pp), "v"(pv) : "memory");
      // output store off the critical path
      out[((size_t)s * trows_out + t0_out + t) * HDIM + r * 32 + tid] = h;
    }
  }

  if (tid < 32) cbuf[s * HDIM + r * 32 + tid] = c_reg;
}

// =====================================================================
// Host launcher
// =====================================================================
extern "C" void kernel_launch(void* const* d_in, const int* in_sizes, int n_in,
                              void* d_out, int out_size, void* d_ws, size_t ws_size,
                              hipStream_t stream) {
  (void)in_sizes; (void)n_in; (void)out_size; (void)ws_size;
  const float* enc  = (const float*)d_in[0];
  const float* Wih0 = (const float*)d_in[1];
  const float* Whh0 = (const float*)d_in[2];
  const float* bih0 = (const float*)d_in[3];
  const float* bhh0 = (const float*)d_in[4];
  const float* Wih1 = (const float*)d_in[5];
  const float* Whh1 = (const float*)d_in[6];
  const float* bih1 = (const float*)d_in[7];
  const float* bhh1 = (const float*)d_in[8];
  float* out = (float*)d_out;

  // workspace layout (floats)
  float* ws  = (float*)d_ws;
  float* xg  = ws;                     // TC*BATCH*G4 = 4,194,304
  float* h1  = ws + 4194304;           // BATCH*TC*HDIM = 1,048,576
  float* st  = ws + 5242880;           // zeroed state region:
  float* hb0 = st;                     //   32*8*512 = 131072 (pair ring L0)
  float* cb0 = st + 131072;            //   8192
  float* hb1 = st + 139264;            //   131072 (pair ring L1)
  float* cb1 = st + 270336;            //   8192
  // total zeroed: 278528 floats

  hipMemsetAsync(st, 0, (size_t)278528 * 4, stream);

  for (int ch = 0; ch < 8; ++ch) {
    gemm_xg<<<dim3(32, 8), 512, 0, stream>>>(enc, Wih0, bih0, bhh0, xg,
                                             512, TFULL, ch * TC);
    lstm_scan<<<NWG, 256, 0, stream>>>(xg, Whh0, h1, TC, 0,
                                       hb0, cb0, ch * TC, TC);
    gemm_xg<<<dim3(32, 8), 512, 0, stream>>>(h1, Wih1, bih1, bhh1, xg,
                                             256, TC, 0);
    lstm_scan<<<NWG, 256, 0, stream>>>(xg, Whh1, out, TFULL, ch * TC,
                                       hb1, cb1, ch * TC, TC);
  }
}

// Round 8
// 3287.136 us; speedup vs baseline: 18.4680x; 1.2795x over previous
//
#include <hip/hip_runtime.h>

// Problem constants
#define BATCH 32
#define TFULL 1024
#define HDIM  256
#define G4    1024   // 4*HDIM
#define TC    128    // timestep chunk
#define NWG   512    // scan workgroups: 32 samples x 16 roles (2 per CU)

// =====================================================================
// GEMM (layer-0 input projection only):
// xg[tl][b][n] = sum_k X[b, t0+tl, k] * W[n, k] + bia[n] + bib[n]
// =====================================================================
__global__ __launch_bounds__(512) void gemm_xg(
    const float* __restrict__ X, const float* __restrict__ W,
    const float* __restrict__ bia, const float* __restrict__ bib,
    float* __restrict__ xg, int K, int trows, int t0)
{
  __shared__ float Xs[16][128];
  __shared__ float Ws[16][128];
  const int tid = threadIdx.x;
  const int m0 = blockIdx.x * 128;
  const int n0 = blockIdx.y * 128;
  const int tx = tid & 15;
  const int ty = tid >> 4;

  float acc[4][8];
#pragma unroll
  for (int i = 0; i < 4; ++i)
#pragma unroll
    for (int j = 0; j < 8; ++j) acc[i][j] = 0.f;

  const int r  = tid >> 2;
  const int kq = tid & 3;
  const int m  = m0 + r;
  const int bX = m & 31;
  const int tl = m >> 5;
  const float* xrow = X + (bX * trows + t0 + tl) * K;
  const float* wrow = W + (n0 + r) * K;

  for (int kt = 0; kt < K; kt += 16) {
    float4 xv = *(const float4*)&xrow[kt + kq * 4];
    float4 wv = *(const float4*)&wrow[kt + kq * 4];
    Xs[kq * 4 + 0][r] = xv.x; Xs[kq * 4 + 1][r] = xv.y;
    Xs[kq * 4 + 2][r] = xv.z; Xs[kq * 4 + 3][r] = xv.w;
    Ws[kq * 4 + 0][r] = wv.x; Ws[kq * 4 + 1][r] = wv.y;
    Ws[kq * 4 + 2][r] = wv.z; Ws[kq * 4 + 3][r] = wv.w;
    __syncthreads();
#pragma unroll
    for (int k = 0; k < 16; ++k) {
      float4 xa = *(const float4*)&Xs[k][ty * 4];
      float4 wa = *(const float4*)&Ws[k][tx * 8];
      float4 wb = *(const float4*)&Ws[k][tx * 8 + 4];
      float xr[4] = {xa.x, xa.y, xa.z, xa.w};
      float wr[8] = {wa.x, wa.y, wa.z, wa.w, wb.x, wb.y, wb.z, wb.w};
#pragma unroll
      for (int i = 0; i < 4; ++i)
#pragma unroll
        for (int j = 0; j < 8; ++j)
          acc[i][j] = fmaf(xr[i], wr[j], acc[i][j]);
    }
    __syncthreads();
  }

  float bb[8];
#pragma unroll
  for (int j = 0; j < 8; ++j) {
    int n = n0 + tx * 8 + j;
    bb[j] = bia[n] + bib[n];
  }
#pragma unroll
  for (int i = 0; i < 4; ++i) {
    int mm = m0 + ty * 4 + i;
    int b = mm & 31, t = mm >> 5;
    float* dst = &xg[(size_t)(t * BATCH + b) * G4 + n0 + tx * 8];
    float4 v0 = make_float4(acc[i][0] + bb[0], acc[i][1] + bb[1],
                            acc[i][2] + bb[2], acc[i][3] + bb[3]);
    float4 v1 = make_float4(acc[i][4] + bb[4], acc[i][5] + bb[5],
                            acc[i][6] + bb[6], acc[i][7] + bb[7]);
    *(float4*)dst = v0;
    *(float4*)(dst + 4) = v1;
  }
}

// Pin 16 float4 (64 floats) into VGPRs from one base pointer.
// Single asm block: 16 loads via offset imms + waitcnt => every output
// is DEFINED at block end (spill-safe), opaque to remat. "=&v" only
// (no tied operands -> compiles on gfx950).
#define PIN_LOAD16(W, PTR)                                             \
  asm volatile(                                                        \
      "global_load_dwordx4 %0,  %16, off\n\t"                          \
      "global_load_dwordx4 %1,  %16, off offset:16\n\t"                \
      "global_load_dwordx4 %2,  %16, off offset:32\n\t"                \
      "global_load_dwordx4 %3,  %16, off offset:48\n\t"                \
      "global_load_dwordx4 %4,  %16, off offset:64\n\t"                \
      "global_load_dwordx4 %5,  %16, off offset:80\n\t"                \
      "global_load_dwordx4 %6,  %16, off offset:96\n\t"                \
      "global_load_dwordx4 %7,  %16, off offset:112\n\t"               \
      "global_load_dwordx4 %8,  %16, off offset:128\n\t"               \
      "global_load_dwordx4 %9,  %16, off offset:144\n\t"               \
      "global_load_dwordx4 %10, %16, off offset:160\n\t"               \
      "global_load_dwordx4 %11, %16, off offset:176\n\t"               \
      "global_load_dwordx4 %12, %16, off offset:192\n\t"               \
      "global_load_dwordx4 %13, %16, off offset:208\n\t"               \
      "global_load_dwordx4 %14, %16, off offset:224\n\t"               \
      "global_load_dwordx4 %15, %16, off offset:240\n\t"               \
      "s_waitcnt vmcnt(0)"                                             \
      : "=&v"(W[0]), "=&v"(W[1]), "=&v"(W[2]), "=&v"(W[3]),            \
        "=&v"(W[4]), "=&v"(W[5]), "=&v"(W[6]), "=&v"(W[7]),            \
        "=&v"(W[8]), "=&v"(W[9]), "=&v"(W[10]), "=&v"(W[11]),          \
        "=&v"(W[12]), "=&v"(W[13]), "=&v"(W[14]), "=&v"(W[15])         \
      : "v"(PTR) : "memory")

// 64-FMA dot of a pinned float4[16] slice against an LDS row segment.
#define DOT64(A0, A1, A2, A3, WREG, HP)                                \
  _Pragma("unroll")                                                    \
  for (int q = 0; q < 16; q += 4) {                                    \
    float4 h0 = (HP)[q+0], h1q = (HP)[q+1];                            \
    float4 h2 = (HP)[q+2], h3q = (HP)[q+3];                            \
    A0 = fmaf(WREG[q+0].x, h0.x, A0);  A0 = fmaf(WREG[q+0].y, h0.y, A0);  \
    A0 = fmaf(WREG[q+0].z, h0.z, A0);  A0 = fmaf(WREG[q+0].w, h0.w, A0);  \
    A1 = fmaf(WREG[q+1].x, h1q.x, A1); A1 = fmaf(WREG[q+1].y, h1q.y, A1); \
    A1 = fmaf(WREG[q+1].z, h1q.z, A1); A1 = fmaf(WREG[q+1].w, h1q.w, A1); \
    A2 = fmaf(WREG[q+2].x, h2.x, A2);  A2 = fmaf(WREG[q+2].y, h2.y, A2);  \
    A2 = fmaf(WREG[q+2].z, h2.z, A2);  A2 = fmaf(WREG[q+2].w, h2.w, A2);  \
    A3 = fmaf(WREG[q+3].x, h3q.x, A3); A3 = fmaf(WREG[q+3].y, h3q.y, A3); \
    A3 = fmaf(WREG[q+3].z, h3q.z, A3); A3 = fmaf(WREG[q+3].w, h3q.w, A3); \
  }

// Poll one mailbox slot (256 (h,tag) pairs) until all tags == G.
// Executed by one 64-lane wave; lane L covers pairs 4L..4L+3.
#define POLL_MB(G, OUT_A, OUT_B, SPTR)                                 \
  {                                                                    \
    for (;;) {                                                         \
      asm volatile(                                                    \
          "global_load_dwordx4 %0, %2, off sc0 sc1\n\t"                \
          "global_load_dwordx4 %1, %3, off sc0 sc1\n\t"                \
          "s_waitcnt vmcnt(0)"                                         \
          : "=&v"(OUT_A), "=&v"(OUT_B)                                 \
          : "v"(SPTR), "v"((SPTR) + 1) : "memory");                    \
      bool ok = (__float_as_uint(OUT_A.y) == (G)) &&                   \
                (__float_as_uint(OUT_A.w) == (G)) &&                   \
                (__float_as_uint(OUT_B.y) == (G)) &&                   \
                (__float_as_uint(OUT_B.w) == (G));                     \
      if (__all(ok)) break;                                            \
    }                                                                  \
  }

// =====================================================================
// Fused two-layer persistent scan. 512 WGs = 32 samples x 16 roles,
// 2 WGs/CU (launch_bounds(256,2) caps VGPRs at 256). WG (s,r) owns h
// columns [r*16, r*16+16) of both layers. Thread: gate gt = tid>>6,
// column jl = lane&15, k-quarter kq = lane>>4 (16-lane broadcast).
// Layer-1 runs one step behind layer-0; skew carries across dispatches
// via global version tags in the mailbox pairs.
//   iteration i (t = T0+i):
//     wave0 polls A@t -> hA = h_A[t-1]; wave1 polls B@t-1 -> hB = h_B[t-2]
//     L0: gates = Whh0.hA + xg0[t] -> h_A[t], publish A@t+1 (early)
//     L1 (step t-1): gates = Wih1.hA + Whh1.hB + b1 -> h_B[t-1],
//         publish B@t, write out[t-1]
// =====================================================================
__global__ __launch_bounds__(256, 2) void lstm_scan2(
    const float* __restrict__ xg0,   // [TC][BATCH][G4] layer-0, bias folded
    const float* __restrict__ Whh0,  // [G4][HDIM]
    const float* __restrict__ Wih1,  // [G4][HDIM]
    const float* __restrict__ Whh1,  // [G4][HDIM]
    const float* __restrict__ bih1, const float* __restrict__ bhh1,
    float* __restrict__ out,         // [B][TFULL][HDIM]
    float* __restrict__ mbA,         // [S][8 slots][512]
    float* __restrict__ mbB,         // [S][8 slots][512]
    float* __restrict__ cbA,         // [S][HDIM]
    float* __restrict__ cbB,         // [S][HDIM]
    int T0, int niter, int nL0)
{
  const int w    = blockIdx.x;
  const int tid  = threadIdx.x;
  const int s    = w & 31;          // sample
  const int r    = w >> 5;          // role: columns [r*16, r*16+16)
  const int gt   = tid >> 6;        // gate type = wave id (i,f,g,o)
  const int lane = tid & 63;
  const int jl   = lane & 15;       // local column
  const int kq   = lane >> 4;       // k quarter (16-lane phase: broadcast)
  const int n    = gt * 256 + r * 16 + jl;

  __shared__ float hA[HDIM];
  __shared__ float hB[HDIM];
  __shared__ float part0[64];
  __shared__ float part1[64];

  // ---- pin 3 weight slices (64 floats each) in VGPRs ----
  float4 w0[16], w1[16], wi[16];
  {
    const float4* p0 = (const float4*)(Whh0 + (size_t)n * HDIM + kq * 64);
    const float4* p1 = (const float4*)(Whh1 + (size_t)n * HDIM + kq * 64);
    const float4* pi = (const float4*)(Wih1 + (size_t)n * HDIM + kq * 64);
    PIN_LOAD16(w0, p0);
    PIN_LOAD16(w1, p1);
    PIN_LOAD16(wi, pi);
  }
  const float b1 = bih1[n] + bhh1[n];

  float cA_reg = 0.f, cB_reg = 0.f;
  if (tid < 16)                cA_reg = cbA[s * HDIM + r * 16 + tid];
  if (tid >= 64 && tid < 80)   cB_reg = cbB[s * HDIM + r * 16 + (tid - 64)];

  float* mA = mbA + (size_t)s * 8 * 512;
  float* mB = mbB + (size_t)s * 8 * 512;

  for (int i = 0; i < niter; ++i) {
    const int t = T0 + i;
    const bool doL0 = (i < nL0);
    const bool doL1 = (t > 0);
    const unsigned gA = (unsigned)t;        // A version consumed
    const unsigned gB = (unsigned)(t - 1);  // B version consumed

    float xv = 0.f;
    if (doL0) xv = xg0[((size_t)(i * BATCH + s) << 10) + n];

    // ---- parallel polls: wave0 -> A@t, wave1 -> B@t-1 ----
    if (tid < 64) {
      const float4* sp = (const float4*)(mA + (size_t)(gA & 7) * 512) + tid * 2;
      float4 A, Bq;
      POLL_MB(gA, A, Bq, sp);
      *(float4*)&hA[tid * 4] = make_float4(A.x, A.z, Bq.x, Bq.z);
    } else if (tid < 128 && doL1) {
      const int l = tid - 64;
      const float4* sp = (const float4*)(mB + (size_t)(gB & 7) * 512) + l * 2;
      float4 A, Bq;
      POLL_MB(gB, A, Bq, sp);
      *(float4*)&hB[l * 4] = make_float4(A.x, A.z, Bq.x, Bq.z);
    }
    __syncthreads();   // sync#1: hA, hB staged

    // ---- L0 dot: Whh0 . hA (64 FMA) ----
    if (doL0) {
      const float4* hp = (const float4*)&hA[kq * 64];
      float a0 = 0.f, a1 = 0.f, a2 = 0.f, a3 = 0.f;
      DOT64(a0, a1, a2, a3, w0, hp);
      float a = (a0 + a1) + (a2 + a3);
      a += __shfl_xor(a, 16);
      a += __shfl_xor(a, 32);
      if (kq == 0) part0[gt * 16 + jl] = a + xv;
    }
    __syncthreads();   // sync#2a: part0 ready

    // ---- L0 finalize + EARLY publish A@t+1 (flight hides under L1) ----
    if (doL0 && tid < 16) {
      float gi = part0[tid],      gf = part0[16 + tid];
      float gg = part0[32 + tid], go = part0[48 + tid];
      float ig = 1.f / (1.f + __expf(-gi));
      float fg = 1.f / (1.f + __expf(-gf));
      float gv = tanhf(gg);
      float og = 1.f / (1.f + __expf(-go));
      cA_reg = fg * cA_reg + ig * gv;
      float h = og * tanhf(cA_reg);
      float2 pv; pv.x = h; pv.y = __uint_as_float((unsigned)(t + 1));
      float* pp = mA + (size_t)((t + 1) & 7) * 512 + (r * 16 + tid) * 2;
      asm volatile("global_store_dwordx2 %0, %1, off sc0 sc1"
                   :: "v"(pp), "v"(pv) : "memory");
    }

    // ---- L1 dots: Wih1 . hA + Whh1 . hB (128 FMA) ----
    if (doL1) {
      const float4* ha = (const float4*)&hA[kq * 64];
      const float4* hb = (const float4*)&hB[kq * 64];
      float a0 = 0.f, a1 = 0.f, a2 = 0.f, a3 = 0.f;
      DOT64(a0, a1, a2, a3, wi, ha);
      DOT64(a0, a1, a2, a3, w1, hb);
      float a = (a0 + a1) + (a2 + a3);
      a += __shfl_xor(a, 16);
      a += __shfl_xor(a, 32);
      if (kq == 0) part1[gt * 16 + jl] = a + b1;
    }
    __syncthreads();   // sync#2b: part1 ready

    // ---- L1 finalize (step t-1): publish B@t, write out ----
    if (doL1 && tid >= 64 && tid < 80) {
      const int l = tid - 64;
      float gi = part1[l],      gf = part1[16 + l];
      float gg = part1[32 + l], go = part1[48 + l];
      float ig = 1.f / (1.f + __expf(-gi));
      float fg = 1.f / (1.f + __expf(-gf));
      float gv = tanhf(gg);
      float og = 1.f / (1.f + __expf(-go));
      cB_reg = fg * cB_reg + ig * gv;
      float h = og * tanhf(cB_reg);
      float2 pv; pv.x = h; pv.y = __uint_as_float((unsigned)t);
      float* pp = mB + (size_t)(t & 7) * 512 + (r * 16 + l) * 2;
      asm volatile("global_store_dwordx2 %0, %1, off sc0 sc1"
                   :: "v"(pp), "v"(pv) : "memory");
      out[((size_t)s * TFULL + (t - 1)) * HDIM + r * 16 + l] = h;
    }
  }

  if (tid < 16)              cbA[s * HDIM + r * 16 + tid] = cA_reg;
  if (tid >= 64 && tid < 80) cbB[s * HDIM + r * 16 + (tid - 64)] = cB_reg;
}

// =====================================================================
// Host launcher
// =====================================================================
extern "C" void kernel_launch(void* const* d_in, const int* in_sizes, int n_in,
                              void* d_out, int out_size, void* d_ws, size_t ws_size,
                              hipStream_t stream) {
  (void)in_sizes; (void)n_in; (void)out_size; (void)ws_size;
  const float* enc  = (const float*)d_in[0];
  const float* Wih0 = (const float*)d_in[1];
  const float* Whh0 = (const float*)d_in[2];
  const float* bih0 = (const float*)d_in[3];
  const float* bhh0 = (const float*)d_in[4];
  const float* Wih1 = (const float*)d_in[5];
  const float* Whh1 = (const float*)d_in[6];
  const float* bih1 = (const float*)d_in[7];
  const float* bhh1 = (const float*)d_in[8];
  float* out = (float*)d_out;

  // workspace layout (floats)
  float* ws  = (float*)d_ws;
  float* xg  = ws;                     // TC*BATCH*G4 = 4,194,304
  float* st  = ws + 4194304;           // zeroed state region:
  float* mbA = st;                     //   32*8*512 = 131072
  float* mbB = st + 131072;            //   131072
  float* cbA = st + 262144;            //   8192
  float* cbB = st + 270336;            //   8192
  // zeroed total: 278528 floats

  hipMemsetAsync(st, 0, (size_t)278528 * 4, stream);

  for (int ch = 0; ch < 8; ++ch) {
    gemm_xg<<<dim3(32, 8), 512, 0, stream>>>(enc, Wih0, bih0, bhh0, xg,
                                             512, TFULL, ch * TC);
    lstm_scan2<<<NWG, 256, 0, stream>>>(xg, Whh0, Wih1, Whh1, bih1, bhh1,
                                        out, mbA, mbB, cbA, cbB,
                                        ch * TC, (ch == 7) ? TC + 1 : TC, TC);
  }
}